// Round 5
// baseline (774.924 us; speedup 1.0000x reference)
//
#include <hip/hip_runtime.h>

static constexpr int N  = 98304;
static constexpr int D  = 128;
static constexpr int E  = 491520;
static constexpr int B  = 16384;
static constexpr int G  = 16;          // nodes owned per edge-block
static constexpr int NBLK = N / G;     // 6144 edge blocks

using f32x4 = __attribute__((ext_vector_type(4))) float;
using s16x8 = __attribute__((ext_vector_type(8))) short;

__device__ __forceinline__ ushort f2bf(float x) {
    unsigned u = __float_as_uint(x);
    return (ushort)((u + 0x7fffu + ((u >> 16) & 1u)) >> 16);
}

__global__ void zero_kernel(float* __restrict__ p, int n) {
    int i = blockIdx.x * blockDim.x + threadIdx.x;
    int stride = gridDim.x * blockDim.x;
    for (; i < n; i += stride) p[i] = 0.f;
}

__global__ void zero_int_kernel(int* __restrict__ p, int n) {
    int i = blockIdx.x * blockDim.x + threadIdx.x;
    int stride = gridDim.x * blockDim.x;
    for (; i < n; i += stride) p[i] = 0;
}

// mir (bf16) = round(src)
__global__ void mirror_kernel(const float4* __restrict__ src, ushort* __restrict__ mir, int npair) {
    int i = blockIdx.x * blockDim.x + threadIdx.x;
    int stride = gridDim.x * blockDim.x;
    for (; i < npair; i += stride) {
        float4 a = src[2 * i], b = src[2 * i + 1];
        union { s16x8 v; ushort u[8]; } pk;
        pk.u[0] = f2bf(a.x); pk.u[1] = f2bf(a.y); pk.u[2] = f2bf(a.z); pk.u[3] = f2bf(a.w);
        pk.u[4] = f2bf(b.x); pk.u[5] = f2bf(b.y); pk.u[6] = f2bf(b.z); pk.u[7] = f2bf(b.w);
        *reinterpret_cast<s16x8*>(mir + (size_t)i * 8) = pk.v;
    }
}

// ---- bucket sort by destination block (dest>>4), once per launch ----

__global__ void hist2_kernel(const int* __restrict__ eto, int* __restrict__ bcnt) {
    int e = blockIdx.x * 256 + threadIdx.x;
    if (e < E) atomicAdd(&bcnt[eto[e] >> 4], 1);
}

__global__ __launch_bounds__(256) void scan1_kernel(const int* __restrict__ cnt,
                                                    int* __restrict__ excl, int* __restrict__ bsum) {
    __shared__ int s[256];
    const int b = blockIdx.x, t = threadIdx.x;
    const int base = b * 1024 + t * 4;
    int4 v = *reinterpret_cast<const int4*>(cnt + base);
    int local = v.x + v.y + v.z + v.w;
    s[t] = local; __syncthreads();
    for (int off = 1; off < 256; off <<= 1) {
        int x = (t >= off) ? s[t - off] : 0;
        __syncthreads();
        s[t] += x;
        __syncthreads();
    }
    int excl_t = s[t] - local;
    if (t == 255) bsum[b] = s[t];
    int4 o;
    o.x = excl_t; o.y = o.x + v.x; o.z = o.y + v.y; o.w = o.z + v.z;
    *reinterpret_cast<int4*>(excl + base) = o;
}

__global__ void scan2_kernel(int* __restrict__ bsum, int nb) {
    if (threadIdx.x == 0) {
        int run = 0;
        for (int i = 0; i < nb; ++i) { int v = bsum[i]; bsum[i] = run; run += v; }
    }
}

__global__ void scan3_kernel(int* __restrict__ excl, const int* __restrict__ bsum) {
    int i = blockIdx.x * 256 + threadIdx.x;
    excl[i] += bsum[i >> 10];
}

// cursor==excl consumed; post-scatter excl[b] = end-of-bucket-b. spack = from | dl<<20.
__global__ void scatter2_kernel(const int* __restrict__ efrom, const int* __restrict__ eto,
                                int* __restrict__ cursor, int* __restrict__ spack) {
    int e = blockIdx.x * 256 + threadIdx.x;
    if (e >= E) return;
    int to = eto[e];
    int p = atomicAdd(&cursor[to >> 4], 1);
    spack[p] = efrom[e] | ((to & 15) << 20);
}

// ---- weight conversion to MFMA B-fragment order ----
// frag: tbl[((kt*8+nt)*64 + lane)*8 + j] = W[n][k], n = nt*16+(lane&15), k = kt*32+(lane>>4)*8+j

__global__ void convWm_kernel(const float* __restrict__ Wm, ushort* __restrict__ Wmf) {
    int gid = blockIdx.x * 256 + threadIdx.x;
    if (gid >= 3 * 32768) return;
    int r = gid >> 15, rem = gid & 32767;
    int n = rem >> 8, k = rem & 255;
    int kt = k >> 5, nt = n >> 4;
    int lane = (n & 15) + (((k >> 3) & 3) << 4);
    int j = k & 7;
    Wmf[r * 32768 + ((kt * 8 + nt) * 64 + lane) * 8 + j] = f2bf(Wm[gid]);
}

__global__ void convW12_kernel(const float* __restrict__ W1, const float* __restrict__ W2,
                               ushort* __restrict__ Wb12) {
    int gid = blockIdx.x * 256 + threadIdx.x;
    if (gid >= 2 * 16384) return;
    int w = gid >> 14, rem = gid & 16383;
    int n = rem >> 7, k = rem & 127;
    int kt = k >> 5, nt = n >> 4;
    int lane = (n & 15) + (((k >> 3) & 3) << 4);
    int j = k & 7;
    const float* W = w ? W2 : W1;
    Wb12[w * 16384 + ((kt * 8 + nt) * 64 + lane) * 8 + j] = f2bf(W[rem]);
}

// ---- edge kernel: per-destination ownership, selector-MFMA reduce ----
// Block b owns nodes [b*16, b*16+16) and their incoming edges spack[lo..hi).
// Per 64-edge chunk: direct-gather A-frags -> 64 MFMA -> msg bf16 -> msgT LDS ->
// S-selector MFMA (4/wave) accumulating per-node sums in registers.
// Epilogue: L_new = Lsrc + sums (plain stores, race-free) + bf16 mirror write.
__global__ __launch_bounds__(256) void edge_v4_kernel(
    const ushort* __restrict__ mirA,
    const float* __restrict__ Lsrc,
    float* __restrict__ Ldst,
    ushort* __restrict__ mirB,
    const ushort* __restrict__ Wb,
    const float* __restrict__ bm_r,
    const int* __restrict__ spack,
    const int* __restrict__ ends,
    const int* __restrict__ ch_ptr)
{
    __shared__ alignas(16) ushort msgT[128 * 64];  // 16 KB, [dim][edge] XOR-swizzled
    __shared__ alignas(16) ushort Smat[16 * 64];   // 2 KB, selector, XOR-swizzled
    const int t = threadIdx.x;
    const int b = blockIdx.x;
    const int v0 = b * G;
    const int lo = (b == 0) ? 0 : ends[b - 1];
    const int hi = ends[b];
    const int nchunk = (hi - lo + 63) >> 6;

    const int wave = t >> 6, lane = t & 63;
    const int col16 = lane & 15;
    const int kq = lane >> 4;
    const int erow = wave * 16 + col16;    // A-frag edge row within chunk
    const int ebase = wave * 16 + kq * 4;  // C-frag edge row base

    const float scale = 1.0f / (float)(ch_ptr[0] - 1);
    float bias[8];
    #pragma unroll
    for (int nt = 0; nt < 8; ++nt) bias[nt] = bm_r[nt * 16 + col16];

    f32x4 r0 = (f32x4){0.f, 0.f, 0.f, 0.f};
    f32x4 r1 = (f32x4){0.f, 0.f, 0.f, 0.f};
    const s16x8* wf = reinterpret_cast<const s16x8*>(Wb);
    char* msgTb = reinterpret_cast<char*>(msgT);
    char* Sb = reinterpret_cast<char*>(Smat);

    for (int cb = 0; cb < nchunk; ++cb) {
        const int base = lo + cb * 64;
        // --- direct global A-frag gather (mirA is L3-resident; 4 kq-lanes/row = 64B line) ---
        int slot = base + erow;
        bool val = slot < hi;
        int spk = spack[val ? slot : lo];
        int from = val ? (spk & 0xFFFFF) : v0;
        int dl   = val ? (spk >> 20) : 0;
        const s16x8* fr = reinterpret_cast<const s16x8*>(mirA + (size_t)from * 128);
        const s16x8* tr = reinterpret_cast<const s16x8*>(mirA + (size_t)(v0 + dl) * 128);
        s16x8 af[8];
        #pragma unroll
        for (int kt = 0; kt < 4; ++kt) af[kt] = fr[kt * 4 + kq];
        #pragma unroll
        for (int kt = 0; kt < 4; ++kt) af[4 + kt] = tr[kt * 4 + kq];

        __syncthreads();   // barrier1: prev-chunk reduce done -> msgT/S writable

        f32x4 acc[8];
        #pragma unroll
        for (int nt = 0; nt < 8; ++nt) acc[nt] = (f32x4){0.f, 0.f, 0.f, 0.f};
        #pragma unroll
        for (int kt = 0; kt < 8; ++kt) {
            #pragma unroll
            for (int nt = 0; nt < 8; ++nt)
                acc[nt] = __builtin_amdgcn_mfma_f32_16x16x32_bf16(af[kt], wf[(kt * 8 + nt) * 64 + lane], acc[nt], 0, 0, 0);
        }

        // msg = relu(acc + bm)*scale -> bf16 -> msgT[d][e] (chunk-XOR swizzle), 8B stores
        #pragma unroll
        for (int nt = 0; nt < 8; ++nt) {
            int d = nt * 16 + col16;
            ushort pk[4];
            #pragma unroll
            for (int j = 0; j < 4; ++j) {
                float m = acc[nt][j] + bias[nt];
                m = (m > 0.f) ? m * scale : 0.f;
                pk[j] = f2bf(m);
            }
            int byte = d * 128 + ((((ebase >> 3) ^ (d & 7)) & 7) << 4) + (ebase & 7) * 2;
            *reinterpret_cast<uint2*>(msgTb + byte) = *reinterpret_cast<uint2*>(pk);
        }

        // wave0 rebuilds selector S[m][e] = (dl[e]==m) (writes 0s too: no zero-pass WAW hazard)
        if (wave == 0) {
            int slot0 = base + lane;
            int dl0 = (slot0 < hi) ? (spack[slot0] >> 20) : -1;
            #pragma unroll
            for (int m = 0; m < 16; ++m) {
                ushort v = (m == dl0) ? (ushort)0x3F80 : (ushort)0;
                int byte = m * 128 + ((((lane >> 3) ^ (m & 7)) & 7) << 4) + (lane & 7) * 2;
                *reinterpret_cast<ushort*>(Sb + byte) = v;
            }
        }
        __syncthreads();   // barrier2: msgT + S ready

        // reduce: C[16 nodes][128 dims] += S(16x64) @ msgT(64x128); wave w owns dims [w*32, w*32+32)
        const int n0 = wave * 32 + col16;
        const int n1 = n0 + 16;
        #pragma unroll
        for (int kt2 = 0; kt2 < 2; ++kt2) {
            int c = kt2 * 4 + kq;
            s16x8 as = *reinterpret_cast<const s16x8*>(Sb + col16 * 128 + (((c ^ (col16 & 7)) & 7) << 4));
            s16x8 b0 = *reinterpret_cast<const s16x8*>(msgTb + n0 * 128 + (((c ^ (n0 & 7)) & 7) << 4));
            s16x8 b1 = *reinterpret_cast<const s16x8*>(msgTb + n1 * 128 + (((c ^ (n1 & 7)) & 7) << 4));
            r0 = __builtin_amdgcn_mfma_f32_16x16x32_bf16(as, b0, r0, 0, 0, 0);
            r1 = __builtin_amdgcn_mfma_f32_16x16x32_bf16(as, b1, r1, 0, 0, 0);
        }
    }

    // epilogue: owner writes L_new and bf16 mirror (no atomics)
    const int dbase = wave * 32 + col16;
    #pragma unroll
    for (int j = 0; j < 4; ++j) {
        int m = kq * 4 + j;
        size_t idx = (size_t)(v0 + m) * 128 + dbase;
        float vA = Lsrc[idx] + r0[j];
        Ldst[idx] = vA;
        mirB[idx] = f2bf(vA);
        float vB = Lsrc[idx + 16] + r1[j];
        Ldst[idx + 16] = vB;
        mirB[idx + 16] = f2bf(vB);
    }
}

__global__ __launch_bounds__(128) void segsum_kernel(
    const float* __restrict__ lat, const int* __restrict__ view, float* __restrict__ y)
{
    const int n = blockIdx.x;
    const int v = view[n];
    atomicAdd(&y[(size_t)v * D + threadIdx.x], lat[(size_t)n * D + threadIdx.x]);
}

// Fused readout: 64 y-rows per block, two MFMA GEMMs through LDS.
__global__ __launch_bounds__(256) void readout_mfma_kernel(
    float* __restrict__ y,
    const ushort* __restrict__ Wb1, const ushort* __restrict__ Wb2,
    const float* __restrict__ b1, const float* __restrict__ b2)
{
    __shared__ alignas(16) ushort hs[64 * 128];
    const int t = threadIdx.x;
    const int r0 = blockIdx.x * 64;
    char* hbase = reinterpret_cast<char*>(hs);
    const float4* y4 = reinterpret_cast<const float4*>(y);

    #pragma unroll
    for (int it = 0; it < 4; ++it) {
        int c = t + it * 256;
        int e = c >> 4, p = c & 15;
        int g = p ^ (e & 15);
        float4 a = y4[(size_t)(r0 + e) * 32 + g * 2];
        float4 bq = y4[(size_t)(r0 + e) * 32 + g * 2 + 1];
        union { s16x8 v; ushort u[8]; } pk;
        pk.u[0] = f2bf(a.x); pk.u[1] = f2bf(a.y); pk.u[2] = f2bf(a.z); pk.u[3] = f2bf(a.w);
        pk.u[4] = f2bf(bq.x); pk.u[5] = f2bf(bq.y); pk.u[6] = f2bf(bq.z); pk.u[7] = f2bf(bq.w);
        *reinterpret_cast<s16x8*>(hbase + e * 256 + p * 16) = pk.v;
    }
    __syncthreads();

    const int wave = t >> 6, lane = t & 63;
    const int rrow = wave * 16 + (lane & 15);
    const int kq = lane >> 4;
    const int rx = rrow & 15;
    const char* hrow = hbase + rrow * 256;
    const int col16 = lane & 15;

    f32x4 acc[8];
    #pragma unroll
    for (int nt = 0; nt < 8; ++nt) acc[nt] = (f32x4){0.f, 0.f, 0.f, 0.f};
    const s16x8* wf1 = reinterpret_cast<const s16x8*>(Wb1);
    #pragma unroll
    for (int kt = 0; kt < 4; ++kt) {
        int C = kt * 4 + kq;
        s16x8 a = *reinterpret_cast<const s16x8*>(hrow + ((C ^ rx) & 15) * 16);
        #pragma unroll
        for (int nt = 0; nt < 8; ++nt)
            acc[nt] = __builtin_amdgcn_mfma_f32_16x16x32_bf16(a, wf1[(kt * 8 + nt) * 64 + lane], acc[nt], 0, 0, 0);
    }
    __syncthreads();

    #pragma unroll
    for (int nt = 0; nt < 8; ++nt) {
        float bias = b1[nt * 16 + col16];
        #pragma unroll
        for (int j = 0; j < 4; ++j) {
            int r = wave * 16 + (lane >> 4) * 4 + j;
            float h = fmaxf(acc[nt][j] + bias, 0.f);
            int colfull = nt * 16 + col16;
            int chunk = colfull >> 3;
            int bo = ((chunk ^ (r & 15)) * 16) + (colfull & 7) * 2;
            *reinterpret_cast<ushort*>(hbase + r * 256 + bo) = f2bf(h);
        }
    }
    __syncthreads();

    f32x4 acc2[8];
    #pragma unroll
    for (int nt = 0; nt < 8; ++nt) acc2[nt] = (f32x4){0.f, 0.f, 0.f, 0.f};
    const s16x8* wf2 = reinterpret_cast<const s16x8*>(Wb2);
    #pragma unroll
    for (int kt = 0; kt < 4; ++kt) {
        int C = kt * 4 + kq;
        s16x8 a = *reinterpret_cast<const s16x8*>(hrow + ((C ^ rx) & 15) * 16);
        #pragma unroll
        for (int nt = 0; nt < 8; ++nt)
            acc2[nt] = __builtin_amdgcn_mfma_f32_16x16x32_bf16(a, wf2[(kt * 8 + nt) * 64 + lane], acc2[nt], 0, 0, 0);
    }

    #pragma unroll
    for (int nt = 0; nt < 8; ++nt) {
        float bias = b2[nt * 16 + col16];
        #pragma unroll
        for (int j = 0; j < 4; ++j) {
            int r = r0 + wave * 16 + (lane >> 4) * 4 + j;
            y[(size_t)r * 128 + nt * 16 + col16] = acc2[nt][j] + bias;
        }
    }
}

extern "C" void kernel_launch(void* const* d_in, const int* in_sizes, int n_in,
                              void* d_out, int out_size, void* d_ws, size_t ws_size,
                              hipStream_t stream) {
    const float* latents = (const float*)d_in[0];
    const float* Wm      = (const float*)d_in[1];
    const float* bm      = (const float*)d_in[2];
    const float* W1      = (const float*)d_in[3];
    const float* b1      = (const float*)d_in[4];
    const float* W2      = (const float*)d_in[5];
    const float* b2      = (const float*)d_in[6];
    const int*   efrom   = (const int*)d_in[7];
    const int*   eto     = (const int*)d_in[8];
    const int*   view    = (const int*)d_in[9];
    const int*   ch      = (const int*)d_in[10];

    // ws: L f32[N*D] | mir0 bf16[N*D] | mir1 bf16[N*D]   (= 96 MiB, same as proven R0 usage)
    float*  L    = (float*)d_ws;
    ushort* mir0 = (ushort*)(L + (size_t)N * D);
    ushort* mir1 = mir0 + (size_t)N * D;

    // d_out doubles as scratch until the readout phase (2.2 MB << 8.4 MB):
    // Wm-frags | spack | bcnt | excl | bsum. Wiped by zero_kernel before segsum.
    char* ob = (char*)d_out;
    ushort* Wmf  = (ushort*)ob;                       // 3*32768 ushorts = 192 KB
    int*    spack = (int*)(ob + 196608);              // E ints = 1.97 MB
    int*    bcnt  = (int*)(ob + 196608 + E * 4);      // 6144 ints
    int*    excl  = bcnt + NBLK;                      // 6144 ints
    int*    bsum  = excl + NBLK;                      // 16 ints
    float*  out   = (float*)d_out;

    const int npair = N * D / 8;

    convWm_kernel<<<384, 256, 0, stream>>>(Wm, Wmf);
    mirror_kernel<<<2048, 256, 0, stream>>>((const float4*)latents, mir0, npair);

    // Bucket edges by destination block (fixed across rounds).
    zero_int_kernel<<<24, 256, 0, stream>>>(bcnt, NBLK);
    hist2_kernel<<<E / 256, 256, 0, stream>>>(eto, bcnt);
    scan1_kernel<<<NBLK / 1024, 256, 0, stream>>>(bcnt, excl, bsum);
    scan2_kernel<<<1, 64, 0, stream>>>(bsum, NBLK / 1024);
    scan3_kernel<<<NBLK / 256, 256, 0, stream>>>(excl, bsum);
    scatter2_kernel<<<E / 256, 256, 0, stream>>>(efrom, eto, excl, spack);
    // post-scatter: excl[b] = end of bucket b

    edge_v4_kernel<<<NBLK, 256, 0, stream>>>(mir0, latents, L, mir1, Wmf,          bm,           spack, excl, ch);
    edge_v4_kernel<<<NBLK, 256, 0, stream>>>(mir1, L,       L, mir0, Wmf + 32768,  bm + D,       spack, excl, ch);
    edge_v4_kernel<<<NBLK, 256, 0, stream>>>(mir0, L,       L, mir1, Wmf + 65536,  bm + 2 * D,   spack, excl, ch);

    // W1/W2 frags into now-dead mir0 space (d_out scratch is about to be wiped).
    ushort* Wb12 = mir0;
    convW12_kernel<<<128, 256, 0, stream>>>(W1, W2, Wb12);

    zero_kernel<<<2048, 256, 0, stream>>>(out, B * D);
    segsum_kernel<<<N, 128, 0, stream>>>(L, view, out);
    readout_mfma_kernel<<<256, 256, 0, stream>>>(out, Wb12, Wb12 + 16384, b1, b2);
}

// Round 6
// 351.885 us; speedup vs baseline: 2.2022x; 2.2022x over previous
//
#include <hip/hip_runtime.h>

static constexpr int N  = 98304;
static constexpr int D  = 128;
static constexpr int E  = 491520;
static constexpr int B  = 16384;

using f32x4 = __attribute__((ext_vector_type(4))) float;
using s16x8 = __attribute__((ext_vector_type(8))) short;

__device__ __forceinline__ ushort f2bf(float x) {
    unsigned u = __float_as_uint(x);
    return (ushort)((u + 0x7fffu + ((u >> 16) & 1u)) >> 16);
}
__device__ __forceinline__ float bflo(unsigned u) { return __uint_as_float(u << 16); }
__device__ __forceinline__ float bfhi(unsigned u) { return __uint_as_float(u & 0xffff0000u); }

__global__ void zero_kernel(float* __restrict__ p, int n) {
    int i = blockIdx.x * blockDim.x + threadIdx.x;
    int stride = gridDim.x * blockDim.x;
    for (; i < n; i += stride) p[i] = 0.f;
}

__global__ void zero_int_kernel(int* __restrict__ p, int n) {
    int i = blockIdx.x * blockDim.x + threadIdx.x;
    int stride = gridDim.x * blockDim.x;
    for (; i < n; i += stride) p[i] = 0;
}

// ---- counting sort of edges by destination node (fixed across rounds) ----

__global__ void hist_kernel(const int* __restrict__ eto, int* __restrict__ cnt) {
    int e = blockIdx.x * 256 + threadIdx.x;
    if (e < E) atomicAdd(&cnt[eto[e]], 1);
}

__global__ __launch_bounds__(256) void scan1_kernel(const int* __restrict__ cnt,
                                                    int* __restrict__ excl, int* __restrict__ bsum) {
    __shared__ int s[256];
    const int b = blockIdx.x, t = threadIdx.x;
    const int base = b * 1024 + t * 4;
    int4 v = *reinterpret_cast<const int4*>(cnt + base);
    int local = v.x + v.y + v.z + v.w;
    s[t] = local; __syncthreads();
    for (int off = 1; off < 256; off <<= 1) {
        int x = (t >= off) ? s[t - off] : 0;
        __syncthreads();
        s[t] += x;
        __syncthreads();
    }
    int excl_t = s[t] - local;
    if (t == 255) bsum[b] = s[t];
    int4 o;
    o.x = excl_t; o.y = o.x + v.x; o.z = o.y + v.y; o.w = o.z + v.z;
    *reinterpret_cast<int4*>(excl + base) = o;
}

__global__ void scan2_kernel(int* __restrict__ bsum, int nb) {
    if (threadIdx.x == 0) {
        int run = 0;
        for (int i = 0; i < nb; ++i) { int v = bsum[i]; bsum[i] = run; run += v; }
    }
}

__global__ void scan3_kernel(int* __restrict__ excl, const int* __restrict__ bsum) {
    int i = blockIdx.x * 256 + threadIdx.x;
    excl[i] += bsum[i >> 10];
}

// cursor==excl consumed; post-scatter excl[v] = end of node v's run.
__global__ void scatter_kernel(const int* __restrict__ efrom, const int* __restrict__ eto,
                               int* __restrict__ cursor, int* __restrict__ sfrom) {
    int e = blockIdx.x * 256 + threadIdx.x;
    if (e >= E) return;
    int p = atomicAdd(&cursor[eto[e]], 1);
    sfrom[p] = efrom[e];
}

// ---- weight conversion ----
// UV table per round r (32768 ushorts): frag[((kt*16+nt)*64+lane)*8+j] = Wsel[n][k],
//   n = (nt&7)*16+(lane&15), k = kt*32+(lane>>4)*8+j, sel col = (nt>>3)*128+k.
__global__ void convUV_kernel(const float* __restrict__ Wm, ushort* __restrict__ Wf) {
    int gid = blockIdx.x * 256 + threadIdx.x;
    if (gid >= 3 * 32768) return;
    int r = gid >> 15, rem = gid & 32767;
    int j = rem & 7, lane = (rem >> 3) & 63, grp = rem >> 9;
    int kt = grp >> 4, nt = grp & 15;
    int n = (nt & 7) * 16 + (lane & 15);
    int k = kt * 32 + (lane >> 4) * 8 + j;
    int col = ((nt >> 3) << 7) + k;
    Wf[gid] = f2bf(Wm[((size_t)r * 128 + n) * 256 + col]);
}

// W1/W2 [128][128] -> frag order (for readout). tbl[w][((kt*8+nt)*64+lane)*8+j] = W[n][k].
__global__ void convW12_kernel(const float* __restrict__ W1, const float* __restrict__ W2,
                               ushort* __restrict__ Wb12) {
    int gid = blockIdx.x * 256 + threadIdx.x;
    if (gid >= 2 * 16384) return;
    int w = gid >> 14, rem = gid & 16383;
    int n = rem >> 7, k = rem & 127;
    int kt = k >> 5, nt = n >> 4;
    int lane = (n & 15) + (((k >> 3) & 3) << 4);
    int j = k & 7;
    const float* W = w ? W2 : W1;
    Wb12[w * 16384 + ((kt * 8 + nt) * 64 + lane) * 8 + j] = f2bf(W[rem]);
}

// ---- per-round dense GEMM: Z[v][0:128] = A[v]@Wf^T (U), Z[v][128:256] = A[v]@Wt^T + bm (V) ----
// A is f32 (latents or L); converted to bf16 at load. Block = 64 rows, wave w: 16 rows x 256 cols.
__global__ __launch_bounds__(256) void uv_kernel(
    const float* __restrict__ Asrc,   // [N][128] f32
    ushort* __restrict__ Z,           // [N][256] bf16
    const ushort* __restrict__ Wft,   // 32768-entry frag table (this round)
    const float* __restrict__ bm_r)   // [128]
{
    const int t = threadIdx.x;
    const int wave = t >> 6, lane = t & 63;
    const int col16 = lane & 15, kq = lane >> 4;
    const int arow = blockIdx.x * 64 + wave * 16 + col16;

    const float4* Ar = reinterpret_cast<const float4*>(Asrc + (size_t)arow * 128);
    f32x4 acc[16];
    #pragma unroll
    for (int nt = 0; nt < 16; ++nt) acc[nt] = (f32x4){0.f, 0.f, 0.f, 0.f};

    const s16x8* wf = reinterpret_cast<const s16x8*>(Wft);
    #pragma unroll
    for (int kt = 0; kt < 4; ++kt) {
        float4 a0 = Ar[kt * 8 + kq * 2];
        float4 a1 = Ar[kt * 8 + kq * 2 + 1];
        union { s16x8 v; ushort u[8]; } pk;
        pk.u[0] = f2bf(a0.x); pk.u[1] = f2bf(a0.y); pk.u[2] = f2bf(a0.z); pk.u[3] = f2bf(a0.w);
        pk.u[4] = f2bf(a1.x); pk.u[5] = f2bf(a1.y); pk.u[6] = f2bf(a1.z); pk.u[7] = f2bf(a1.w);
        #pragma unroll
        for (int nt = 0; nt < 16; ++nt)
            acc[nt] = __builtin_amdgcn_mfma_f32_16x16x32_bf16(pk.v, wf[(kt * 16 + nt) * 64 + lane], acc[nt], 0, 0, 0);
    }

    const int rbase = blockIdx.x * 64 + wave * 16 + kq * 4;
    #pragma unroll
    for (int nt = 0; nt < 16; ++nt) {
        float bias = (nt >= 8) ? bm_r[(nt - 8) * 16 + col16] : 0.f;
        int cfull = ((nt >> 3) << 7) + (nt & 7) * 16 + col16;
        #pragma unroll
        for (int j = 0; j < 4; ++j)
            Z[(size_t)(rbase + j) * 256 + cfull] = f2bf(acc[nt][j] + bias);
    }
}

// ---- edge pass: one WAVE per destination node; no atomics/LDS/barriers ----
// L[v] = Lsrc[v] + scale * sum_{e->v} relu(U[from_e] + V[v])
__global__ __launch_bounds__(256) void edge_sum_kernel(
    const ushort* __restrict__ Z,     // [N][256] bf16 (U | V+bm)
    const float* __restrict__ Lsrc,
    float* __restrict__ Ldst,
    const int* __restrict__ sfrom,    // edge sources sorted by dest
    const int* __restrict__ ends,     // ends[v] = end of v's run
    const int* __restrict__ ch_ptr)
{
    const int t = threadIdx.x;
    const int wave = t >> 6, lane = t & 63;
    const int v = blockIdx.x * 4 + wave;
    const int lo = (v == 0) ? 0 : ends[v - 1];
    const int hi = ends[v];
    const float scale = 1.0f / (float)(ch_ptr[0] - 1);

    unsigned vv = *reinterpret_cast<const unsigned*>(Z + (size_t)v * 256 + 128 + lane * 2);
    const float v0 = bflo(vv), v1 = bfhi(vv);

    float a0 = 0.f, a1 = 0.f;
    int e = lo;
    for (; e + 2 <= hi; e += 2) {
        int f0 = sfrom[e], f1 = sfrom[e + 1];
        unsigned u0 = *reinterpret_cast<const unsigned*>(Z + (size_t)f0 * 256 + lane * 2);
        unsigned u1 = *reinterpret_cast<const unsigned*>(Z + (size_t)f1 * 256 + lane * 2);
        a0 += fmaxf(bflo(u0) + v0, 0.f) + fmaxf(bflo(u1) + v0, 0.f);
        a1 += fmaxf(bfhi(u0) + v1, 0.f) + fmaxf(bfhi(u1) + v1, 0.f);
    }
    if (e < hi) {
        int f0 = sfrom[e];
        unsigned u0 = *reinterpret_cast<const unsigned*>(Z + (size_t)f0 * 256 + lane * 2);
        a0 += fmaxf(bflo(u0) + v0, 0.f);
        a1 += fmaxf(bfhi(u0) + v1, 0.f);
    }

    float2 lold = *reinterpret_cast<const float2*>(Lsrc + (size_t)v * 128 + lane * 2);
    float2 out;
    out.x = lold.x + scale * a0;
    out.y = lold.y + scale * a1;
    *reinterpret_cast<float2*>(Ldst + (size_t)v * 128 + lane * 2) = out;
}

__global__ __launch_bounds__(128) void segsum_kernel(
    const float* __restrict__ lat, const int* __restrict__ view, float* __restrict__ y)
{
    const int n = blockIdx.x;
    const int v = view[n];
    atomicAdd(&y[(size_t)v * D + threadIdx.x], lat[(size_t)n * D + threadIdx.x]);
}

// Fused readout: 64 y-rows per block, two MFMA GEMMs through LDS.
__global__ __launch_bounds__(256) void readout_mfma_kernel(
    float* __restrict__ y,
    const ushort* __restrict__ Wb1, const ushort* __restrict__ Wb2,
    const float* __restrict__ b1, const float* __restrict__ b2)
{
    __shared__ alignas(16) ushort hs[64 * 128];
    const int t = threadIdx.x;
    const int r0 = blockIdx.x * 64;
    char* hbase = reinterpret_cast<char*>(hs);
    const float4* y4 = reinterpret_cast<const float4*>(y);

    #pragma unroll
    for (int it = 0; it < 4; ++it) {
        int c = t + it * 256;
        int e = c >> 4, p = c & 15;
        int g = p ^ (e & 15);
        float4 a = y4[(size_t)(r0 + e) * 32 + g * 2];
        float4 bq = y4[(size_t)(r0 + e) * 32 + g * 2 + 1];
        union { s16x8 v; ushort u[8]; } pk;
        pk.u[0] = f2bf(a.x); pk.u[1] = f2bf(a.y); pk.u[2] = f2bf(a.z); pk.u[3] = f2bf(a.w);
        pk.u[4] = f2bf(bq.x); pk.u[5] = f2bf(bq.y); pk.u[6] = f2bf(bq.z); pk.u[7] = f2bf(bq.w);
        *reinterpret_cast<s16x8*>(hbase + e * 256 + p * 16) = pk.v;
    }
    __syncthreads();

    const int wave = t >> 6, lane = t & 63;
    const int rrow = wave * 16 + (lane & 15);
    const int kq = lane >> 4;
    const int rx = rrow & 15;
    const char* hrow = hbase + rrow * 256;
    const int col16 = lane & 15;

    f32x4 acc[8];
    #pragma unroll
    for (int nt = 0; nt < 8; ++nt) acc[nt] = (f32x4){0.f, 0.f, 0.f, 0.f};
    const s16x8* wf1 = reinterpret_cast<const s16x8*>(Wb1);
    #pragma unroll
    for (int kt = 0; kt < 4; ++kt) {
        int C = kt * 4 + kq;
        s16x8 a = *reinterpret_cast<const s16x8*>(hrow + ((C ^ rx) & 15) * 16);
        #pragma unroll
        for (int nt = 0; nt < 8; ++nt)
            acc[nt] = __builtin_amdgcn_mfma_f32_16x16x32_bf16(a, wf1[(kt * 8 + nt) * 64 + lane], acc[nt], 0, 0, 0);
    }
    __syncthreads();

    #pragma unroll
    for (int nt = 0; nt < 8; ++nt) {
        float bias = b1[nt * 16 + col16];
        #pragma unroll
        for (int j = 0; j < 4; ++j) {
            int r = wave * 16 + (lane >> 4) * 4 + j;
            float h = fmaxf(acc[nt][j] + bias, 0.f);
            int colfull = nt * 16 + col16;
            int chunk = colfull >> 3;
            int bo = ((chunk ^ (r & 15)) * 16) + (colfull & 7) * 2;
            *reinterpret_cast<ushort*>(hbase + r * 256 + bo) = f2bf(h);
        }
    }
    __syncthreads();

    f32x4 acc2[8];
    #pragma unroll
    for (int nt = 0; nt < 8; ++nt) acc2[nt] = (f32x4){0.f, 0.f, 0.f, 0.f};
    const s16x8* wf2 = reinterpret_cast<const s16x8*>(Wb2);
    #pragma unroll
    for (int kt = 0; kt < 4; ++kt) {
        int C = kt * 4 + kq;
        s16x8 a = *reinterpret_cast<const s16x8*>(hrow + ((C ^ rx) & 15) * 16);
        #pragma unroll
        for (int nt = 0; nt < 8; ++nt)
            acc2[nt] = __builtin_amdgcn_mfma_f32_16x16x32_bf16(a, wf2[(kt * 8 + nt) * 64 + lane], acc2[nt], 0, 0, 0);
    }

    #pragma unroll
    for (int nt = 0; nt < 8; ++nt) {
        float bias = b2[nt * 16 + col16];
        #pragma unroll
        for (int j = 0; j < 4; ++j) {
            int r = r0 + wave * 16 + (lane >> 4) * 4 + j;
            y[(size_t)r * 128 + nt * 16 + col16] = acc2[nt][j] + bias;
        }
    }
}

extern "C" void kernel_launch(void* const* d_in, const int* in_sizes, int n_in,
                              void* d_out, int out_size, void* d_ws, size_t ws_size,
                              hipStream_t stream) {
    const float* latents = (const float*)d_in[0];
    const float* Wm      = (const float*)d_in[1];
    const float* bm      = (const float*)d_in[2];
    const float* W1      = (const float*)d_in[3];
    const float* b1      = (const float*)d_in[4];
    const float* W2      = (const float*)d_in[5];
    const float* b2      = (const float*)d_in[6];
    const int*   efrom   = (const int*)d_in[7];
    const int*   eto     = (const int*)d_in[8];
    const int*   view    = (const int*)d_in[9];
    const int*   ch      = (const int*)d_in[10];

    // ws: L f32[N*128] (50.33 MB) | Z bf16[N*256] (50.33 MB)  == 100.66 MB (proven footprint)
    float*  L = (float*)d_ws;
    ushort* Z = (ushort*)(L + (size_t)N * D);

    // d_out doubles as scratch until zero_kernel wipes it (all uses end before that):
    // WUVf 3*32768 us | cnt[N] | excl[N] | bsum[128] | sfrom[E]   (~2.95 MB < 8.39 MB)
    char* ob = (char*)d_out;
    ushort* WUVf = (ushort*)ob;
    int*    cnt   = (int*)(ob + 196608);
    int*    excl  = cnt + N;
    int*    bsum  = excl + N;
    int*    sfrom = bsum + 128;
    float*  out   = (float*)d_out;

    // Sort edges by destination (fixed across rounds).
    convUV_kernel<<<384, 256, 0, stream>>>(Wm, WUVf);
    zero_int_kernel<<<384, 256, 0, stream>>>(cnt, N);
    hist_kernel<<<E / 256, 256, 0, stream>>>(eto, cnt);
    scan1_kernel<<<N / 1024, 256, 0, stream>>>(cnt, excl, bsum);
    scan2_kernel<<<1, 64, 0, stream>>>(bsum, N / 1024);
    scan3_kernel<<<N / 256, 256, 0, stream>>>(excl, bsum);
    scatter_kernel<<<E / 256, 256, 0, stream>>>(efrom, eto, excl, sfrom);
    // post-scatter: excl[v] = end of node v's edge run

    // Round 0: A = latents (f32 input), L updated from latents
    uv_kernel<<<N / 64, 256, 0, stream>>>(latents, Z, WUVf, bm);
    edge_sum_kernel<<<N / 4, 256, 0, stream>>>(Z, latents, L, sfrom, excl, ch);
    // Rounds 1,2: in-place L (ownership makes it race-free)
    uv_kernel<<<N / 64, 256, 0, stream>>>(L, Z, WUVf + 32768, bm + D);
    edge_sum_kernel<<<N / 4, 256, 0, stream>>>(Z, L, L, sfrom, excl, ch);
    uv_kernel<<<N / 64, 256, 0, stream>>>(L, Z, WUVf + 65536, bm + 2 * D);
    edge_sum_kernel<<<N / 4, 256, 0, stream>>>(Z, L, L, sfrom, excl, ch);

    // Readout. Z is dead now; reuse it for W1/W2 frag tables (d_out is about to be wiped).
    ushort* Wb12 = Z;
    convW12_kernel<<<128, 256, 0, stream>>>(W1, W2, Wb12);
    zero_kernel<<<2048, 256, 0, stream>>>(out, B * D);
    segsum_kernel<<<N, 128, 0, stream>>>(L, view, out);
    readout_mfma_kernel<<<256, 256, 0, stream>>>(out, Wb12, Wb12 + 16384, b1, b2);
}

// Round 7
// 307.820 us; speedup vs baseline: 2.5175x; 1.1432x over previous
//
#include <hip/hip_runtime.h>

static constexpr int N  = 98304;
static constexpr int D  = 128;
static constexpr int E  = 491520;
static constexpr int B  = 16384;

using f32x4 = __attribute__((ext_vector_type(4))) float;
using s16x8 = __attribute__((ext_vector_type(8))) short;

__device__ __forceinline__ ushort f2bf(float x) {
    unsigned u = __float_as_uint(x);
    return (ushort)((u + 0x7fffu + ((u >> 16) & 1u)) >> 16);
}
__device__ __forceinline__ float bflo(unsigned u) { return __uint_as_float(u << 16); }
__device__ __forceinline__ float bfhi(unsigned u) { return __uint_as_float(u & 0xffff0000u); }

// ---- setup: zero both histogram arrays (cnt[N] | vcnt[B] contiguous) ----
__global__ void zero2_kernel(int* __restrict__ p) {
    int i = blockIdx.x * 256 + threadIdx.x;
    if (i < N + B) p[i] = 0;
}

// ---- dual histogram: edges by dest, nodes by view ----
__global__ void hist2_kernel(const int* __restrict__ eto, const int* __restrict__ view,
                             int* __restrict__ cnt, int* __restrict__ vcnt) {
    int gid = blockIdx.x * 256 + threadIdx.x;
    if (gid < E) atomicAdd(&cnt[eto[gid]], 1);
    else if (gid < E + N) atomicAdd(&vcnt[view[gid - E]], 1);
}

// ---- dual scan, stage 1: blocks 0..95 nodes (N/1024), 96..111 views (B/1024) ----
__global__ __launch_bounds__(256) void scan1_kernel(const int* __restrict__ cnt, int* __restrict__ excl,
                                                    const int* __restrict__ vcnt, int* __restrict__ vexcl,
                                                    int* __restrict__ bsum) {
    __shared__ int s[256];
    const int b = blockIdx.x, t = threadIdx.x;
    const int* src; int* dst; int base;
    if (b < 96) { src = cnt;  dst = excl;  base = b * 1024 + t * 4; }
    else        { src = vcnt; dst = vexcl; base = (b - 96) * 1024 + t * 4; }
    int4 v = *reinterpret_cast<const int4*>(src + base);
    int local = v.x + v.y + v.z + v.w;
    s[t] = local; __syncthreads();
    for (int off = 1; off < 256; off <<= 1) {
        int x = (t >= off) ? s[t - off] : 0;
        __syncthreads();
        s[t] += x;
        __syncthreads();
    }
    int excl_t = s[t] - local;
    if (t == 255) bsum[b] = s[t];
    int4 o;
    o.x = excl_t; o.y = o.x + v.x; o.z = o.y + v.y; o.w = o.z + v.z;
    *reinterpret_cast<int4*>(dst + base) = o;
}

__global__ void scan2_kernel(int* __restrict__ bsum) {
    int t = threadIdx.x;
    if (t == 0) { int run = 0; for (int i = 0;  i < 96;  ++i) { int v = bsum[i]; bsum[i] = run; run += v; } }
    if (t == 1) { int run = 0; for (int i = 96; i < 112; ++i) { int v = bsum[i]; bsum[i] = run; run += v; } }
}

// blocks 0..383 nodes, 384..447 views
__global__ void scan3_kernel(int* __restrict__ excl, int* __restrict__ vexcl,
                             const int* __restrict__ bsum) {
    int b = blockIdx.x, t = threadIdx.x;
    if (b < 384) { int i = b * 256 + t; excl[i] += bsum[i >> 10]; }
    else         { int i = (b - 384) * 256 + t; vexcl[i] += bsum[96 + (i >> 10)]; }
}

// dual scatter; cursors consumed -> excl/vexcl become run-ends.
__global__ void scatter2_kernel(const int* __restrict__ efrom, const int* __restrict__ eto,
                                const int* __restrict__ view,
                                int* __restrict__ ecur, int* __restrict__ vcur,
                                int* __restrict__ sfrom, int* __restrict__ perm) {
    int gid = blockIdx.x * 256 + threadIdx.x;
    if (gid < E) {
        int p = atomicAdd(&ecur[eto[gid]], 1);
        sfrom[p] = efrom[gid];
    } else if (gid < E + N) {
        int n = gid - E;
        int p = atomicAdd(&vcur[view[n]], 1);
        perm[p] = n;
    }
}

// ---- weight conversion ----
// UV table per round r: frag[((kt*16+nt)*64+lane)*8+j] = Wsel[n][k],
//   n = (nt&7)*16+(lane&15), k = kt*32+(lane>>4)*8+j, col = (nt>>3)*128+k.
__global__ void convUV_kernel(const float* __restrict__ Wm, ushort* __restrict__ Wf) {
    int gid = blockIdx.x * 256 + threadIdx.x;
    if (gid >= 3 * 32768) return;
    int r = gid >> 15, rem = gid & 32767;
    int j = rem & 7, lane = (rem >> 3) & 63, grp = rem >> 9;
    int kt = grp >> 4, nt = grp & 15;
    int n = (nt & 7) * 16 + (lane & 15);
    int k = kt * 32 + (lane >> 4) * 8 + j;
    int col = ((nt >> 3) << 7) + k;
    Wf[gid] = f2bf(Wm[((size_t)r * 128 + n) * 256 + col]);
}

__global__ void convW12_kernel(const float* __restrict__ W1, const float* __restrict__ W2,
                               ushort* __restrict__ Wb12) {
    int gid = blockIdx.x * 256 + threadIdx.x;
    if (gid >= 2 * 16384) return;
    int w = gid >> 14, rem = gid & 16383;
    int n = rem >> 7, k = rem & 127;
    int kt = k >> 5, nt = n >> 4;
    int lane = (n & 15) + (((k >> 3) & 3) << 4);
    int j = k & 7;
    const float* W = w ? W2 : W1;
    Wb12[w * 16384 + ((kt * 8 + nt) * 64 + lane) * 8 + j] = f2bf(W[rem]);
}

// ---- per-round dense GEMM: Z[v][0:128]=A[v]@Wf^T (U), Z[v][128:256]=A[v]@Wt^T+bm (V) ----
__global__ __launch_bounds__(256) void uv_kernel(
    const float* __restrict__ Asrc, ushort* __restrict__ Z,
    const ushort* __restrict__ Wft, const float* __restrict__ bm_r)
{
    const int t = threadIdx.x;
    const int wave = t >> 6, lane = t & 63;
    const int col16 = lane & 15, kq = lane >> 4;
    const int arow = blockIdx.x * 64 + wave * 16 + col16;

    // hoist all A loads (independent) before the pack+MFMA chain
    const float4* Ar = reinterpret_cast<const float4*>(Asrc + (size_t)arow * 128);
    float4 areg[8];
    #pragma unroll
    for (int kt = 0; kt < 4; ++kt) {
        areg[2 * kt]     = Ar[kt * 8 + kq * 2];
        areg[2 * kt + 1] = Ar[kt * 8 + kq * 2 + 1];
    }

    f32x4 acc[16];
    #pragma unroll
    for (int nt = 0; nt < 16; ++nt) acc[nt] = (f32x4){0.f, 0.f, 0.f, 0.f};

    const s16x8* wf = reinterpret_cast<const s16x8*>(Wft);
    #pragma unroll
    for (int kt = 0; kt < 4; ++kt) {
        float4 a0 = areg[2 * kt], a1 = areg[2 * kt + 1];
        union { s16x8 v; ushort u[8]; } pk;
        pk.u[0] = f2bf(a0.x); pk.u[1] = f2bf(a0.y); pk.u[2] = f2bf(a0.z); pk.u[3] = f2bf(a0.w);
        pk.u[4] = f2bf(a1.x); pk.u[5] = f2bf(a1.y); pk.u[6] = f2bf(a1.z); pk.u[7] = f2bf(a1.w);
        #pragma unroll
        for (int nt = 0; nt < 16; ++nt)
            acc[nt] = __builtin_amdgcn_mfma_f32_16x16x32_bf16(pk.v, wf[(kt * 16 + nt) * 64 + lane], acc[nt], 0, 0, 0);
    }

    const int rbase = blockIdx.x * 64 + wave * 16 + kq * 4;
    #pragma unroll
    for (int nt = 0; nt < 16; ++nt) {
        float bias = (nt >= 8) ? bm_r[(nt - 8) * 16 + col16] : 0.f;
        int cfull = ((nt >> 3) << 7) + (nt & 7) * 16 + col16;
        #pragma unroll
        for (int j = 0; j < 4; ++j)
            Z[(size_t)(rbase + j) * 256 + cfull] = f2bf(acc[nt][j] + bias);
    }
}

// ---- edge pass: 16 nodes/block, 4 nodes/wave, unroll-4 masked gather ----
// L[v] = Lsrc[v] + scale * sum_{e->v} relu(U[from_e] + V[v])
__global__ __launch_bounds__(256) void edge_sum_kernel(
    const ushort* __restrict__ Z, const float* __restrict__ Lsrc, float* __restrict__ Ldst,
    const int* __restrict__ sfrom, const int* __restrict__ ends, const int* __restrict__ ch_ptr)
{
    const int t = threadIdx.x;
    const int wave = t >> 6, lane = t & 63;
    const float scale = 1.0f / (float)(ch_ptr[0] - 1);

    #pragma unroll
    for (int i = 0; i < 4; ++i) {
        const int v = blockIdx.x * 16 + wave * 4 + i;
        const int lo = (v == 0) ? 0 : ends[v - 1];
        const int hi = ends[v];

        unsigned vv = *reinterpret_cast<const unsigned*>(Z + (size_t)v * 256 + 128 + lane * 2);
        const float v0 = bflo(vv), v1 = bfhi(vv);

        float a0 = 0.f, a1 = 0.f;
        for (int e = lo; e < hi; e += 4) {
            int last = hi - 1;
            int e1 = (e + 1 < hi) ? e + 1 : last;
            int e2 = (e + 2 < hi) ? e + 2 : last;
            int e3 = (e + 3 < hi) ? e + 3 : last;
            float m1 = (e + 1 < hi) ? 1.f : 0.f;
            float m2 = (e + 2 < hi) ? 1.f : 0.f;
            float m3 = (e + 3 < hi) ? 1.f : 0.f;
            int f0 = sfrom[e], f1 = sfrom[e1], f2 = sfrom[e2], f3 = sfrom[e3];
            unsigned u0 = *reinterpret_cast<const unsigned*>(Z + (size_t)f0 * 256 + lane * 2);
            unsigned u1 = *reinterpret_cast<const unsigned*>(Z + (size_t)f1 * 256 + lane * 2);
            unsigned u2 = *reinterpret_cast<const unsigned*>(Z + (size_t)f2 * 256 + lane * 2);
            unsigned u3 = *reinterpret_cast<const unsigned*>(Z + (size_t)f3 * 256 + lane * 2);
            a0 += fmaxf(bflo(u0) + v0, 0.f) + m1 * fmaxf(bflo(u1) + v0, 0.f)
                + m2 * fmaxf(bflo(u2) + v0, 0.f) + m3 * fmaxf(bflo(u3) + v0, 0.f);
            a1 += fmaxf(bfhi(u0) + v1, 0.f) + m1 * fmaxf(bfhi(u1) + v1, 0.f)
                + m2 * fmaxf(bfhi(u2) + v1, 0.f) + m3 * fmaxf(bfhi(u3) + v1, 0.f);
        }

        float2 lold = *reinterpret_cast<const float2*>(Lsrc + (size_t)v * 128 + lane * 2);
        float2 outv;
        outv.x = lold.x + scale * a0;
        outv.y = lold.y + scale * a1;
        *reinterpret_cast<float2*>(Ldst + (size_t)v * 128 + lane * 2) = outv;
    }
}

// ---- segment sum via view-sorted perm: one wave per view, no atomics ----
// Writes EVERY view row (0 for empty views) -> no pre-zero needed.
__global__ __launch_bounds__(256) void segsum_sorted_kernel(
    const float* __restrict__ L, const int* __restrict__ perm,
    const int* __restrict__ vends, float* __restrict__ y)
{
    const int t = threadIdx.x;
    const int wave = t >> 6, lane = t & 63;
    const int v = blockIdx.x * 4 + wave;
    const int lo = (v == 0) ? 0 : vends[v - 1];
    const int hi = vends[v];

    float a0 = 0.f, a1 = 0.f;
    for (int e = lo; e < hi; e += 2) {
        int last = hi - 1;
        int e1 = (e + 1 < hi) ? e + 1 : last;
        float m1 = (e + 1 < hi) ? 1.f : 0.f;
        int n0 = perm[e], n1 = perm[e1];
        float2 x0 = *reinterpret_cast<const float2*>(L + (size_t)n0 * 128 + lane * 2);
        float2 x1 = *reinterpret_cast<const float2*>(L + (size_t)n1 * 128 + lane * 2);
        a0 += x0.x + m1 * x1.x;
        a1 += x0.y + m1 * x1.y;
    }
    float2 o; o.x = a0; o.y = a1;
    *reinterpret_cast<float2*>(y + (size_t)v * 128 + lane * 2) = o;
}

// ---- fused readout: reads y (ws), writes final output to d_out ----
__global__ __launch_bounds__(256) void readout_mfma_kernel(
    const float* __restrict__ y, float* __restrict__ outp,
    const ushort* __restrict__ Wb1, const ushort* __restrict__ Wb2,
    const float* __restrict__ b1, const float* __restrict__ b2)
{
    __shared__ alignas(16) ushort hs[64 * 128];
    const int t = threadIdx.x;
    const int r0 = blockIdx.x * 64;
    char* hbase = reinterpret_cast<char*>(hs);
    const float4* y4 = reinterpret_cast<const float4*>(y);

    #pragma unroll
    for (int it = 0; it < 4; ++it) {
        int c = t + it * 256;
        int e = c >> 4, p = c & 15;
        int g = p ^ (e & 15);
        float4 a = y4[(size_t)(r0 + e) * 32 + g * 2];
        float4 bq = y4[(size_t)(r0 + e) * 32 + g * 2 + 1];
        union { s16x8 v; ushort u[8]; } pk;
        pk.u[0] = f2bf(a.x); pk.u[1] = f2bf(a.y); pk.u[2] = f2bf(a.z); pk.u[3] = f2bf(a.w);
        pk.u[4] = f2bf(bq.x); pk.u[5] = f2bf(bq.y); pk.u[6] = f2bf(bq.z); pk.u[7] = f2bf(bq.w);
        *reinterpret_cast<s16x8*>(hbase + e * 256 + p * 16) = pk.v;
    }
    __syncthreads();

    const int wave = t >> 6, lane = t & 63;
    const int rrow = wave * 16 + (lane & 15);
    const int kq = lane >> 4;
    const int rx = rrow & 15;
    const char* hrow = hbase + rrow * 256;
    const int col16 = lane & 15;

    f32x4 acc[8];
    #pragma unroll
    for (int nt = 0; nt < 8; ++nt) acc[nt] = (f32x4){0.f, 0.f, 0.f, 0.f};
    const s16x8* wf1 = reinterpret_cast<const s16x8*>(Wb1);
    #pragma unroll
    for (int kt = 0; kt < 4; ++kt) {
        int C = kt * 4 + kq;
        s16x8 a = *reinterpret_cast<const s16x8*>(hrow + ((C ^ rx) & 15) * 16);
        #pragma unroll
        for (int nt = 0; nt < 8; ++nt)
            acc[nt] = __builtin_amdgcn_mfma_f32_16x16x32_bf16(a, wf1[(kt * 8 + nt) * 64 + lane], acc[nt], 0, 0, 0);
    }
    __syncthreads();

    #pragma unroll
    for (int nt = 0; nt < 8; ++nt) {
        float bias = b1[nt * 16 + col16];
        #pragma unroll
        for (int j = 0; j < 4; ++j) {
            int r = wave * 16 + (lane >> 4) * 4 + j;
            float h = fmaxf(acc[nt][j] + bias, 0.f);
            int colfull = nt * 16 + col16;
            int chunk = colfull >> 3;
            int bo = ((chunk ^ (r & 15)) * 16) + (colfull & 7) * 2;
            *reinterpret_cast<ushort*>(hbase + r * 256 + bo) = f2bf(h);
        }
    }
    __syncthreads();

    f32x4 acc2[8];
    #pragma unroll
    for (int nt = 0; nt < 8; ++nt) acc2[nt] = (f32x4){0.f, 0.f, 0.f, 0.f};
    const s16x8* wf2 = reinterpret_cast<const s16x8*>(Wb2);
    #pragma unroll
    for (int kt = 0; kt < 4; ++kt) {
        int C = kt * 4 + kq;
        s16x8 a = *reinterpret_cast<const s16x8*>(hrow + ((C ^ rx) & 15) * 16);
        #pragma unroll
        for (int nt = 0; nt < 8; ++nt)
            acc2[nt] = __builtin_amdgcn_mfma_f32_16x16x32_bf16(a, wf2[(kt * 8 + nt) * 64 + lane], acc2[nt], 0, 0, 0);
    }

    #pragma unroll
    for (int nt = 0; nt < 8; ++nt) {
        float bias = b2[nt * 16 + col16];
        #pragma unroll
        for (int j = 0; j < 4; ++j) {
            int r = r0 + wave * 16 + (lane >> 4) * 4 + j;
            outp[(size_t)r * 128 + nt * 16 + col16] = acc2[nt][j] + bias;
        }
    }
}

extern "C" void kernel_launch(void* const* d_in, const int* in_sizes, int n_in,
                              void* d_out, int out_size, void* d_ws, size_t ws_size,
                              hipStream_t stream) {
    const float* latents = (const float*)d_in[0];
    const float* Wm      = (const float*)d_in[1];
    const float* bm      = (const float*)d_in[2];
    const float* W1      = (const float*)d_in[3];
    const float* b1      = (const float*)d_in[4];
    const float* W2      = (const float*)d_in[5];
    const float* b2      = (const float*)d_in[6];
    const int*   efrom   = (const int*)d_in[7];
    const int*   eto     = (const int*)d_in[8];
    const int*   view    = (const int*)d_in[9];
    const int*   ch      = (const int*)d_in[10];

    // ws (96 MiB exactly, proven): L f32[N*128] | Z bf16[N*256].
    // After final edge_sum Z is dead: y f32[B*128] and Wb12 reuse its space.
    float*  L  = (float*)d_ws;
    ushort* Z  = (ushort*)(L + (size_t)N * D);
    float*  yb = (float*)Z;                              // B*128 f32 = 8.39 MB
    ushort* Wb12 = (ushort*)((char*)Z + 8388608);        // 64 KB

    // d_out scratch (never zeroed; readout is d_out's only writer, covers all of it):
    // WUVf | cnt[N] | vcnt[B] | excl[N] | vexcl[B] | bsum[112] | sfrom[E] | perm[N]
    char* ob = (char*)d_out;
    ushort* WUVf = (ushort*)ob;                          // 196,608 B
    int* cnt   = (int*)(ob + 196608);                    // N
    int* vcnt  = cnt + N;                                // B (contiguous with cnt)
    int* excl  = vcnt + B;                               // N
    int* vexcl = excl + N;                               // B (contiguous with excl)
    int* bsum  = vexcl + B;                              // 112 (+pad)
    int* sfrom = bsum + 128;                             // E
    int* perm  = sfrom + E;                              // N   (total ~3.5 MB < 8.39 MB)
    float* outp = (float*)d_out;

    // Setup: weight frags + dual counting sort (edges by dest, nodes by view).
    convUV_kernel<<<384, 256, 0, stream>>>(Wm, WUVf);
    zero2_kernel<<<(N + B) / 256, 256, 0, stream>>>(cnt);
    hist2_kernel<<<(E + N) / 256, 256, 0, stream>>>(eto, view, cnt, vcnt);
    scan1_kernel<<<112, 256, 0, stream>>>(cnt, excl, vcnt, vexcl, bsum);
    scan2_kernel<<<1, 64, 0, stream>>>(bsum);
    scan3_kernel<<<448, 256, 0, stream>>>(excl, vexcl, bsum);
    scatter2_kernel<<<(E + N) / 256, 256, 0, stream>>>(efrom, eto, view, excl, vexcl, sfrom, perm);
    // post-scatter: excl[v] = end of node v's edge run; vexcl[s] = end of view s's node run

    // Three message-passing rounds.
    uv_kernel<<<N / 64, 256, 0, stream>>>(latents, Z, WUVf, bm);
    edge_sum_kernel<<<N / 16, 256, 0, stream>>>(Z, latents, L, sfrom, excl, ch);
    uv_kernel<<<N / 64, 256, 0, stream>>>(L, Z, WUVf + 32768, bm + D);
    edge_sum_kernel<<<N / 16, 256, 0, stream>>>(Z, L, L, sfrom, excl, ch);
    uv_kernel<<<N / 64, 256, 0, stream>>>(L, Z, WUVf + 65536, bm + 2 * D);
    edge_sum_kernel<<<N / 16, 256, 0, stream>>>(Z, L, L, sfrom, excl, ch);

    // Readout: Z dead -> yb/Wb12 live there. segsum writes every y row (no pre-zero).
    convW12_kernel<<<128, 256, 0, stream>>>(W1, W2, Wb12);
    segsum_sorted_kernel<<<B / 4, 256, 0, stream>>>(L, perm, vexcl, yb);
    readout_mfma_kernel<<<B / 64, 256, 0, stream>>>(yb, outp, Wb12, Wb12 + 16384, b1, b2);
}

// Round 8
// 283.142 us; speedup vs baseline: 2.7369x; 1.0872x over previous
//
#include <hip/hip_runtime.h>

static constexpr int N  = 98304;
static constexpr int D  = 128;
static constexpr int E  = 491520;
static constexpr int B  = 16384;

using f32x4 = __attribute__((ext_vector_type(4))) float;
using s16x8 = __attribute__((ext_vector_type(8))) short;

typedef __attribute__((address_space(3))) void lds_void;
typedef const __attribute__((address_space(1))) void gbl_void;

__device__ __forceinline__ ushort f2bf(float x) {
    unsigned u = __float_as_uint(x);
    return (ushort)((u + 0x7fffu + ((u >> 16) & 1u)) >> 16);
}
__device__ __forceinline__ float bflo(unsigned u) { return __uint_as_float(u << 16); }
__device__ __forceinline__ float bfhi(unsigned u) { return __uint_as_float(u & 0xffff0000u); }

// ---- setup: zero both histogram arrays (cnt[N] | vcnt[B] contiguous) ----
__global__ void zero2_kernel(int* __restrict__ p) {
    int i = blockIdx.x * 256 + threadIdx.x;
    if (i < N + B) p[i] = 0;
}

// ---- dual histogram: edges by dest, nodes by view ----
__global__ void hist2_kernel(const int* __restrict__ eto, const int* __restrict__ view,
                             int* __restrict__ cnt, int* __restrict__ vcnt) {
    int gid = blockIdx.x * 256 + threadIdx.x;
    if (gid < E) atomicAdd(&cnt[eto[gid]], 1);
    else if (gid < E + N) atomicAdd(&vcnt[view[gid - E]], 1);
}

// ---- dual scan, stage 1: blocks 0..95 nodes, 96..111 views ----
__global__ __launch_bounds__(256) void scan1_kernel(const int* __restrict__ cnt, int* __restrict__ excl,
                                                    const int* __restrict__ vcnt, int* __restrict__ vexcl,
                                                    int* __restrict__ bsum) {
    __shared__ int s[256];
    const int b = blockIdx.x, t = threadIdx.x;
    const int* src; int* dst; int base;
    if (b < 96) { src = cnt;  dst = excl;  base = b * 1024 + t * 4; }
    else        { src = vcnt; dst = vexcl; base = (b - 96) * 1024 + t * 4; }
    int4 v = *reinterpret_cast<const int4*>(src + base);
    int local = v.x + v.y + v.z + v.w;
    s[t] = local; __syncthreads();
    for (int off = 1; off < 256; off <<= 1) {
        int x = (t >= off) ? s[t - off] : 0;
        __syncthreads();
        s[t] += x;
        __syncthreads();
    }
    int excl_t = s[t] - local;
    if (t == 255) bsum[b] = s[t];
    int4 o;
    o.x = excl_t; o.y = o.x + v.x; o.z = o.y + v.y; o.w = o.z + v.z;
    *reinterpret_cast<int4*>(dst + base) = o;
}

__global__ void scan2_kernel(int* __restrict__ bsum) {
    int t = threadIdx.x;
    if (t == 0) { int run = 0; for (int i = 0;  i < 96;  ++i) { int v = bsum[i]; bsum[i] = run; run += v; } }
    if (t == 1) { int run = 0; for (int i = 96; i < 112; ++i) { int v = bsum[i]; bsum[i] = run; run += v; } }
}

__global__ void scan3_kernel(int* __restrict__ excl, int* __restrict__ vexcl,
                             const int* __restrict__ bsum) {
    int b = blockIdx.x, t = threadIdx.x;
    if (b < 384) { int i = b * 256 + t; excl[i] += bsum[i >> 10]; }
    else         { int i = (b - 384) * 256 + t; vexcl[i] += bsum[96 + (i >> 10)]; }
}

__global__ void scatter2_kernel(const int* __restrict__ efrom, const int* __restrict__ eto,
                                const int* __restrict__ view,
                                int* __restrict__ ecur, int* __restrict__ vcur,
                                int* __restrict__ sfrom, int* __restrict__ perm) {
    int gid = blockIdx.x * 256 + threadIdx.x;
    if (gid < E) {
        int p = atomicAdd(&ecur[eto[gid]], 1);
        sfrom[p] = efrom[gid];
    } else if (gid < E + N) {
        int n = gid - E;
        int p = atomicAdd(&vcur[view[n]], 1);
        perm[p] = n;
    }
}

// ---- weight conversion ----
// UV table per round r: frag[((kt*16+nt)*64+lane)*8+j] = Wsel[n][k],
//   n = (nt&7)*16+(lane&15), k = kt*32+(lane>>4)*8+j, col = (nt>>3)*128+k.
__global__ void convUV_kernel(const float* __restrict__ Wm, ushort* __restrict__ Wf) {
    int gid = blockIdx.x * 256 + threadIdx.x;
    if (gid >= 3 * 32768) return;
    int r = gid >> 15, rem = gid & 32767;
    int j = rem & 7, lane = (rem >> 3) & 63, grp = rem >> 9;
    int kt = grp >> 4, nt = grp & 15;
    int n = (nt & 7) * 16 + (lane & 15);
    int k = kt * 32 + (lane >> 4) * 8 + j;
    int col = ((nt >> 3) << 7) + k;
    Wf[gid] = f2bf(Wm[((size_t)r * 128 + n) * 256 + col]);
}

__global__ void convW12_kernel(const float* __restrict__ W1, const float* __restrict__ W2,
                               ushort* __restrict__ Wb12) {
    int gid = blockIdx.x * 256 + threadIdx.x;
    if (gid >= 2 * 16384) return;
    int w = gid >> 14, rem = gid & 16383;
    int n = rem >> 7, k = rem & 127;
    int kt = k >> 5, nt = n >> 4;
    int lane = (n & 15) + (((k >> 3) & 3) << 4);
    int j = k & 7;
    const float* W = w ? W2 : W1;
    Wb12[w * 16384 + ((kt * 8 + nt) * 64 + lane) * 8 + j] = f2bf(W[rem]);
}

// ---- per-round dense GEMM: Z[v][0:128]=A[v]@Wf^T (U), Z[v][128:256]=A[v]@Wt^T+bm (V) ----
// 512 threads = 8 waves, 128 rows/block. Round's 64 KB frag table staged in LDS once;
// B-frags become conflict-free ds_read_b128 instead of L2 round-trips.
__global__ __launch_bounds__(512) void uv_kernel(
    const float* __restrict__ Asrc, ushort* __restrict__ Z,
    const ushort* __restrict__ Wft, const float* __restrict__ bm_r)
{
    __shared__ alignas(16) ushort wlds[32768];   // 64 KB
    const int t = threadIdx.x;

    #pragma unroll
    for (int it = 0; it < 8; ++it) {
        int idx = t + it * 512;   // 16B chunk id; lane-linear LDS dest
        __builtin_amdgcn_global_load_lds((gbl_void*)(Wft + idx * 8),
                                         (lds_void*)(wlds + idx * 8), 16, 0, 0);
    }

    const int wave = t >> 6, lane = t & 63;
    const int col16 = lane & 15, kq = lane >> 4;
    const int arow = blockIdx.x * 128 + wave * 16 + col16;

    // hoist A loads (independent of LDS staging)
    const float4* Ar = reinterpret_cast<const float4*>(Asrc + (size_t)arow * 128);
    float4 areg[8];
    #pragma unroll
    for (int kt = 0; kt < 4; ++kt) {
        areg[2 * kt]     = Ar[kt * 8 + kq * 2];
        areg[2 * kt + 1] = Ar[kt * 8 + kq * 2 + 1];
    }

    f32x4 acc[16];
    #pragma unroll
    for (int nt = 0; nt < 16; ++nt) acc[nt] = (f32x4){0.f, 0.f, 0.f, 0.f};

    __syncthreads();   // wlds ready (compiler orders lgkmcnt for the lds-loads)

    const char* wb = reinterpret_cast<const char*>(wlds);
    #pragma unroll
    for (int kt = 0; kt < 4; ++kt) {
        float4 a0 = areg[2 * kt], a1 = areg[2 * kt + 1];
        union { s16x8 v; ushort u[8]; } pk;
        pk.u[0] = f2bf(a0.x); pk.u[1] = f2bf(a0.y); pk.u[2] = f2bf(a0.z); pk.u[3] = f2bf(a0.w);
        pk.u[4] = f2bf(a1.x); pk.u[5] = f2bf(a1.y); pk.u[6] = f2bf(a1.z); pk.u[7] = f2bf(a1.w);
        #pragma unroll
        for (int nt = 0; nt < 16; ++nt) {
            s16x8 bfr = *reinterpret_cast<const s16x8*>(wb + (((kt * 16 + nt) * 64 + lane) << 4));
            acc[nt] = __builtin_amdgcn_mfma_f32_16x16x32_bf16(pk.v, bfr, acc[nt], 0, 0, 0);
        }
    }

    const int rbase = blockIdx.x * 128 + wave * 16 + kq * 4;
    #pragma unroll
    for (int nt = 0; nt < 16; ++nt) {
        float bias = (nt >= 8) ? bm_r[(nt - 8) * 16 + col16] : 0.f;
        int cfull = ((nt >> 3) << 7) + (nt & 7) * 16 + col16;
        #pragma unroll
        for (int j = 0; j < 4; ++j)
            Z[(size_t)(rbase + j) * 256 + cfull] = f2bf(acc[nt][j] + bias);
    }
}

// ---- edge pass: 16 nodes/block, 4 nodes/wave; hoisted loads, mask-free main loop ----
// L[v] = Lsrc[v] + scale * sum_{e->v} relu(U[from_e] + V[v])
__global__ __launch_bounds__(256) void edge_sum_kernel(
    const ushort* __restrict__ Z, const float* __restrict__ Lsrc, float* __restrict__ Ldst,
    const int* __restrict__ sfrom, const int* __restrict__ ends, const int* __restrict__ ch_ptr)
{
    const int t = threadIdx.x;
    const int wave = t >> 6, lane = t & 63;
    const float scale = 1.0f / (float)(ch_ptr[0] - 1);
    const int v0 = blockIdx.x * 16 + wave * 4;

    // hoisted independent loads: 5 bounds + 4 V-rows + 4 L-rows all in flight
    int bnd[5];
    bnd[0] = (v0 == 0) ? 0 : ends[v0 - 1];
    #pragma unroll
    for (int i = 0; i < 4; ++i) bnd[i + 1] = ends[v0 + i];
    unsigned vv[4]; float2 lold[4];
    #pragma unroll
    for (int i = 0; i < 4; ++i) {
        vv[i] = *reinterpret_cast<const unsigned*>(Z + (size_t)(v0 + i) * 256 + 128 + lane * 2);
        lold[i] = *reinterpret_cast<const float2*>(Lsrc + (size_t)(v0 + i) * 128 + lane * 2);
    }

    #pragma unroll
    for (int i = 0; i < 4; ++i) {
        const int lo = bnd[i], hi = bnd[i + 1];
        const float vl = bflo(vv[i]), vh = bfhi(vv[i]);
        float a0 = 0.f, a1 = 0.f;
        int e = lo;
        for (; e + 4 <= hi; e += 4) {
            int f0 = sfrom[e], f1 = sfrom[e + 1], f2 = sfrom[e + 2], f3 = sfrom[e + 3];
            unsigned u0 = *reinterpret_cast<const unsigned*>(Z + (size_t)f0 * 256 + lane * 2);
            unsigned u1 = *reinterpret_cast<const unsigned*>(Z + (size_t)f1 * 256 + lane * 2);
            unsigned u2 = *reinterpret_cast<const unsigned*>(Z + (size_t)f2 * 256 + lane * 2);
            unsigned u3 = *reinterpret_cast<const unsigned*>(Z + (size_t)f3 * 256 + lane * 2);
            a0 += fmaxf(bflo(u0) + vl, 0.f) + fmaxf(bflo(u1) + vl, 0.f)
                + fmaxf(bflo(u2) + vl, 0.f) + fmaxf(bflo(u3) + vl, 0.f);
            a1 += fmaxf(bfhi(u0) + vh, 0.f) + fmaxf(bfhi(u1) + vh, 0.f)
                + fmaxf(bfhi(u2) + vh, 0.f) + fmaxf(bfhi(u3) + vh, 0.f);
        }
        for (; e < hi; ++e) {
            int f0 = sfrom[e];
            unsigned u0 = *reinterpret_cast<const unsigned*>(Z + (size_t)f0 * 256 + lane * 2);
            a0 += fmaxf(bflo(u0) + vl, 0.f);
            a1 += fmaxf(bfhi(u0) + vh, 0.f);
        }
        float2 o;
        o.x = lold[i].x + scale * a0;
        o.y = lold[i].y + scale * a1;
        *reinterpret_cast<float2*>(Ldst + (size_t)(v0 + i) * 128 + lane * 2) = o;
    }
}

// ---- segment sum via view-sorted perm: one wave per view, no atomics ----
__global__ __launch_bounds__(256) void segsum_sorted_kernel(
    const float* __restrict__ L, const int* __restrict__ perm,
    const int* __restrict__ vends, float* __restrict__ y)
{
    const int t = threadIdx.x;
    const int wave = t >> 6, lane = t & 63;
    const int v = blockIdx.x * 4 + wave;
    const int lo = (v == 0) ? 0 : vends[v - 1];
    const int hi = vends[v];

    float a0 = 0.f, a1 = 0.f;
    for (int e = lo; e < hi; e += 2) {
        int last = hi - 1;
        int e1 = (e + 1 < hi) ? e + 1 : last;
        float m1 = (e + 1 < hi) ? 1.f : 0.f;
        int n0 = perm[e], n1 = perm[e1];
        float2 x0 = *reinterpret_cast<const float2*>(L + (size_t)n0 * 128 + lane * 2);
        float2 x1 = *reinterpret_cast<const float2*>(L + (size_t)n1 * 128 + lane * 2);
        a0 += x0.x + m1 * x1.x;
        a1 += x0.y + m1 * x1.y;
    }
    float2 o; o.x = a0; o.y = a1;
    *reinterpret_cast<float2*>(y + (size_t)v * 128 + lane * 2) = o;
}

// ---- fused readout: reads y (ws), writes final output to d_out ----
__global__ __launch_bounds__(256) void readout_mfma_kernel(
    const float* __restrict__ y, float* __restrict__ outp,
    const ushort* __restrict__ Wb1, const ushort* __restrict__ Wb2,
    const float* __restrict__ b1, const float* __restrict__ b2)
{
    __shared__ alignas(16) ushort hs[64 * 128];
    const int t = threadIdx.x;
    const int r0 = blockIdx.x * 64;
    char* hbase = reinterpret_cast<char*>(hs);
    const float4* y4 = reinterpret_cast<const float4*>(y);

    #pragma unroll
    for (int it = 0; it < 4; ++it) {
        int c = t + it * 256;
        int e = c >> 4, p = c & 15;
        int g = p ^ (e & 15);
        float4 a = y4[(size_t)(r0 + e) * 32 + g * 2];
        float4 bq = y4[(size_t)(r0 + e) * 32 + g * 2 + 1];
        union { s16x8 v; ushort u[8]; } pk;
        pk.u[0] = f2bf(a.x); pk.u[1] = f2bf(a.y); pk.u[2] = f2bf(a.z); pk.u[3] = f2bf(a.w);
        pk.u[4] = f2bf(bq.x); pk.u[5] = f2bf(bq.y); pk.u[6] = f2bf(bq.z); pk.u[7] = f2bf(bq.w);
        *reinterpret_cast<s16x8*>(hbase + e * 256 + p * 16) = pk.v;
    }
    __syncthreads();

    const int wave = t >> 6, lane = t & 63;
    const int rrow = wave * 16 + (lane & 15);
    const int kq = lane >> 4;
    const int rx = rrow & 15;
    const char* hrow = hbase + rrow * 256;
    const int col16 = lane & 15;

    f32x4 acc[8];
    #pragma unroll
    for (int nt = 0; nt < 8; ++nt) acc[nt] = (f32x4){0.f, 0.f, 0.f, 0.f};
    const s16x8* wf1 = reinterpret_cast<const s16x8*>(Wb1);
    #pragma unroll
    for (int kt = 0; kt < 4; ++kt) {
        int C = kt * 4 + kq;
        s16x8 a = *reinterpret_cast<const s16x8*>(hrow + ((C ^ rx) & 15) * 16);
        #pragma unroll
        for (int nt = 0; nt < 8; ++nt)
            acc[nt] = __builtin_amdgcn_mfma_f32_16x16x32_bf16(a, wf1[(kt * 8 + nt) * 64 + lane], acc[nt], 0, 0, 0);
    }
    __syncthreads();

    #pragma unroll
    for (int nt = 0; nt < 8; ++nt) {
        float bias = b1[nt * 16 + col16];
        #pragma unroll
        for (int j = 0; j < 4; ++j) {
            int r = wave * 16 + (lane >> 4) * 4 + j;
            float h = fmaxf(acc[nt][j] + bias, 0.f);
            int colfull = nt * 16 + col16;
            int chunk = colfull >> 3;
            int bo = ((chunk ^ (r & 15)) * 16) + (colfull & 7) * 2;
            *reinterpret_cast<ushort*>(hbase + r * 256 + bo) = f2bf(h);
        }
    }
    __syncthreads();

    f32x4 acc2[8];
    #pragma unroll
    for (int nt = 0; nt < 8; ++nt) acc2[nt] = (f32x4){0.f, 0.f, 0.f, 0.f};
    const s16x8* wf2 = reinterpret_cast<const s16x8*>(Wb2);
    #pragma unroll
    for (int kt = 0; kt < 4; ++kt) {
        int C = kt * 4 + kq;
        s16x8 a = *reinterpret_cast<const s16x8*>(hrow + ((C ^ rx) & 15) * 16);
        #pragma unroll
        for (int nt = 0; nt < 8; ++nt)
            acc2[nt] = __builtin_amdgcn_mfma_f32_16x16x32_bf16(a, wf2[(kt * 8 + nt) * 64 + lane], acc2[nt], 0, 0, 0);
    }

    #pragma unroll
    for (int nt = 0; nt < 8; ++nt) {
        float bias = b2[nt * 16 + col16];
        #pragma unroll
        for (int j = 0; j < 4; ++j) {
            int r = r0 + wave * 16 + (lane >> 4) * 4 + j;
            outp[(size_t)r * 128 + nt * 16 + col16] = acc2[nt][j] + bias;
        }
    }
}

extern "C" void kernel_launch(void* const* d_in, const int* in_sizes, int n_in,
                              void* d_out, int out_size, void* d_ws, size_t ws_size,
                              hipStream_t stream) {
    const float* latents = (const float*)d_in[0];
    const float* Wm      = (const float*)d_in[1];
    const float* bm      = (const float*)d_in[2];
    const float* W1      = (const float*)d_in[3];
    const float* b1      = (const float*)d_in[4];
    const float* W2      = (const float*)d_in[5];
    const float* b2      = (const float*)d_in[6];
    const int*   efrom   = (const int*)d_in[7];
    const int*   eto     = (const int*)d_in[8];
    const int*   view    = (const int*)d_in[9];
    const int*   ch      = (const int*)d_in[10];

    // ws (100.66 MB, proven): L f32[N*128] | Z bf16[N*256].
    // After final edge_sum Z is dead: y f32[B*128] and Wb12 reuse its space.
    float*  L  = (float*)d_ws;
    ushort* Z  = (ushort*)(L + (size_t)N * D);
    float*  yb = (float*)Z;                              // B*128 f32 = 8.39 MB
    ushort* Wb12 = (ushort*)((char*)Z + 8388608);        // 64 KB

    // d_out scratch (readout is d_out's only writer, covers all of it):
    char* ob = (char*)d_out;
    ushort* WUVf = (ushort*)ob;                          // 196,608 B
    int* cnt   = (int*)(ob + 196608);                    // N
    int* vcnt  = cnt + N;                                // B
    int* excl  = vcnt + B;                               // N
    int* vexcl = excl + N;                               // B
    int* bsum  = vexcl + B;                              // 112 (+pad)
    int* sfrom = bsum + 128;                             // E
    int* perm  = sfrom + E;                              // N
    float* outp = (float*)d_out;

    // Setup: weight frags + dual counting sort (edges by dest, nodes by view).
    convUV_kernel<<<384, 256, 0, stream>>>(Wm, WUVf);
    zero2_kernel<<<(N + B) / 256, 256, 0, stream>>>(cnt);
    hist2_kernel<<<(E + N) / 256, 256, 0, stream>>>(eto, view, cnt, vcnt);
    scan1_kernel<<<112, 256, 0, stream>>>(cnt, excl, vcnt, vexcl, bsum);
    scan2_kernel<<<1, 64, 0, stream>>>(bsum);
    scan3_kernel<<<448, 256, 0, stream>>>(excl, vexcl, bsum);
    scatter2_kernel<<<(E + N) / 256, 256, 0, stream>>>(efrom, eto, view, excl, vexcl, sfrom, perm);
    // post-scatter: excl[v] = end of node v's edge run; vexcl[s] = end of view s's node run

    // Three message-passing rounds.
    uv_kernel<<<N / 128, 512, 0, stream>>>(latents, Z, WUVf, bm);
    edge_sum_kernel<<<N / 16, 256, 0, stream>>>(Z, latents, L, sfrom, excl, ch);
    uv_kernel<<<N / 128, 512, 0, stream>>>(L, Z, WUVf + 32768, bm + D);
    edge_sum_kernel<<<N / 16, 256, 0, stream>>>(Z, L, L, sfrom, excl, ch);
    uv_kernel<<<N / 128, 512, 0, stream>>>(L, Z, WUVf + 65536, bm + 2 * D);
    edge_sum_kernel<<<N / 16, 256, 0, stream>>>(Z, L, L, sfrom, excl, ch);

    // Readout: Z dead -> yb/Wb12 live there.
    convW12_kernel<<<128, 256, 0, stream>>>(W1, W2, Wb12);
    segsum_sorted_kernel<<<B / 4, 256, 0, stream>>>(L, perm, vexcl, yb);
    readout_mfma_kernel<<<B / 64, 256, 0, stream>>>(yb, outp, Wb12, Wb12 + 16384, b1, b2);
}